// Round 2
// baseline (194.952 us; speedup 1.0000x reference)
//
#include <hip/hip_runtime.h>

// RegLoss: l1(masked preds, targets) + 0.1 * mse(masked edge directions)
// preds, targets: [128, 1024, 151] fp32. Output: 1 fp32 scalar.
//
// Identities:
//   targets * (targets != 0) == targets       (masking targets is identity)
//   (m*pd - m*td)^2 == m*(pd - td)^2          (m in {0,1})
//   diff/(len+tiny) == (d2 > 0 ? diff*rsq(d2) : 0)  (~1e-7 rel; thresh 2.4e-2)
//
// R8: abandon global_load_lds for the stream. Evidence: R6 (16 waves/CU,
// depth-2 LDS dbuf) and R7 (32 waves/CU, depth-1) have IDENTICAL duration
// (64.2 vs 64.4 us), VALUBusy (18.8%), and hbm_gbps (1250) -- doubling
// wave concurrency changed nothing, so the kernel is NOT latency-bound;
// it sits on a ~2.5 TB/s bandwidth wall on the load path (158 MB / 64 us),
// while HBM reads only 1.25 TB/s (half the footprint is L3-resident) and
// every other pipe is idle. The proven 6.3 TB/s ceiling (m13) was measured
// with plain vector loads -> VGPR, not the LDS-DMA path. Theory: the
// global_load_lds return path caps this stream.
//
// New structure (T14 async-STAGE split): plain float4 loads -> regs ->
// ds_write_b128. Per chunk:
//   vmcnt auto-wait (regs arrive) -> ds_write x6 -> l1 term FROM REGS
//   -> issue chunk c+1 loads (latency hides under edge compute)
//   -> edge gather from LDS.
// Benefits: (a) stream rides the plain-load path; (b) depth-2 pipeline
// lives in 24 VGPRs, LDS stays single-buffered -> 19.3 KB/block keeps
// 8 blocks/CU (whole grid co-resident); (c) l1 no longer reads LDS at all
// (-6 ds_read_b128/chunk). VGPR must stay <=64 for 8 waves/SIMD.

#define N_ROWS   (128 * 1024)
#define ROW      151
#define N_EDGES  47
#define GRID     2048
#define BLOCK    256
#define CHUNKS   4                     // 2048 blk * 4 waves * 4 chunks * 4 rows
#define CHUNK_ROWS 4
#define CHUNK_DW (CHUNK_ROWS * ROW)    // 604 dwords per array per chunk
#define CHUNK_TASKS (CHUNK_ROWS * N_EDGES) // 188
#define BUF_DW (2 * CHUNK_DW)          // [preds 604][targets 604] = 4832 B

#if __has_builtin(__builtin_amdgcn_rsqf)
__device__ __forceinline__ float fast_rsq(float x) { return __builtin_amdgcn_rsqf(x); }
#else
__device__ __forceinline__ float fast_rsq(float x) {
    float r; asm volatile("v_rsq_f32 %0, %1" : "=v"(r) : "v"(x)); return r;
}
#endif

__device__ __forceinline__ float4 ldg4(const float* __restrict__ p) {
    return *reinterpret_cast<const float4*>(p);
}
__device__ __forceinline__ void st4(float* __restrict__ p, float4 v) {
    *reinterpret_cast<float4*>(p) = v;
}

// packed: low16 = parent*3 (dword offset in row), high16 = child*3
#define E(p, c) ((unsigned)((p) * 3) | ((unsigned)((c) * 3) << 16))
__constant__ unsigned c_edge[N_EDGES] = {
    E(0,1),  E(1,2),  E(2,3),  E(3,29), E(1,5),  E(5,6),  E(6,8),  E(8,9),
    E(8,13), E(8,17), E(8,21), E(8,25), E(9,10), E(10,11),E(11,12),E(13,14),
    E(14,15),E(15,16),E(17,18),E(18,19),E(19,20),E(21,22),E(22,23),E(23,24),
    E(25,26),E(26,27),E(27,28),E(29,30),E(29,34),E(29,38),E(29,42),E(29,46),
    E(30,31),E(31,32),E(32,33),E(34,35),E(35,36),E(36,37),E(38,39),E(39,40),
    E(40,41),E(42,43),E(43,44),E(44,45),E(46,47),E(47,48),E(48,49)};

struct TaskDesc { int act[3], roff[3], pi[3], ci[3], me[3]; };

__device__ __forceinline__ void acc_l1(float4 pv, float4 tv, float& l1) {
    float a0 = (tv.x != 0.f) ? pv.x : 0.f;
    float a1 = (tv.y != 0.f) ? pv.y : 0.f;
    float a2 = (tv.z != 0.f) ? pv.z : 0.f;
    float a3 = (tv.w != 0.f) ? pv.w : 0.f;
    l1 += fabsf(a0 - tv.x) + fabsf(a1 - tv.y)
        + fabsf(a2 - tv.z) + fabsf(a3 - tv.w);
}

// 188 edge tasks from LDS, mask applied at read time.
__device__ __forceinline__ void compute_edges(
        const float* __restrict__ B, const TaskDesc& td, float& vel) {
    const float* __restrict__ Bp = B;
    const float* __restrict__ Bt = B + CHUNK_DW;
#pragma unroll
    for (int k = 0; k < 3; ++k) {
        if (td.act[k]) {
            const float* __restrict__ Rp = Bp + td.roff[k];
            const float* __restrict__ Rt = Bt + td.roff[k];
            int pi = td.pi[k], ci = td.ci[k], me = td.me[k];
            float tpx = Rt[pi], tpy = Rt[pi + 1], tpz = Rt[pi + 2];
            float tcx = Rt[ci], tcy = Rt[ci + 1], tcz = Rt[ci + 2];
            float ppx = Rp[pi], ppy = Rp[pi + 1], ppz = Rp[pi + 2];
            float pcx = Rp[ci], pcy = Rp[ci + 1], pcz = Rp[ci + 2];
            // masked preds
            float apx = (tpx != 0.f) ? ppx : 0.f;
            float apy = (tpy != 0.f) ? ppy : 0.f;
            float apz = (tpz != 0.f) ? ppz : 0.f;
            float acx = (tcx != 0.f) ? pcx : 0.f;
            float acy = (tcy != 0.f) ? pcy : 0.f;
            float acz = (tcz != 0.f) ? pcz : 0.f;
            float pdx = apx - acx, pdy = apy - acy, pdz = apz - acz;
            float tdx = tpx - tcx, tdy = tpy - tcy, tdz = tpz - tcz;
            float pd2 = pdx * pdx + pdy * pdy + pdz * pdz;
            float td2 = tdx * tdx + tdy * tdy + tdz * tdz;
            float pinv = (pd2 > 0.f) ? fast_rsq(pd2) : 0.f;
            float tinv = (td2 > 0.f) ? fast_rsq(td2) : 0.f;
            float dx = pdx * pinv - tdx * tinv;
            float dy = pdy * pinv - tdy * tinv;
            float dz = pdz * pinv - tdz * tinv;
            float m0 = (Rt[me]      != 0.f) ? 1.f : 0.f;
            float m1 = (Rt[me + 47] != 0.f) ? 1.f : 0.f;
            float m2 = (Rt[me + 94] != 0.f) ? 1.f : 0.f;
            vel += m0 * dx * dx + m1 * dy * dy + m2 * dz * dz;
        }
    }
}

__global__ __launch_bounds__(BLOCK, 8) void reg_loss_main(
        const float* __restrict__ preds, const float* __restrict__ targets,
        float* __restrict__ wsL, float* __restrict__ wsV) {
    __shared__ float S[4][BUF_DW];         // 4 waves x 4832B = 19.3 KB/block
    __shared__ float redL[4], redV[4];

    const int t = threadIdx.x;
    const int lane = t & 63;
    const int wave = t >> 6;
    float* B = &S[wave][0];

    const long long wb =
        (long long)(blockIdx.x * 4 + wave) * (CHUNKS * CHUNK_DW);
    const float* gp = preds + wb;
    const float* gt = targets + wb;

    const int l4 = lane * 4;
    const bool tail = lane < 23;           // 23*16B = 368B tail (604-512 dw)

    // per-lane edge-task descriptors (fixed across chunks)
    TaskDesc td;
#pragma unroll
    for (int k = 0; k < 3; ++k) {
        int task = lane + k * 64;
        td.act[k] = task < CHUNK_TASKS;
        int r = task / N_EDGES;
        int e = task - r * N_EDGES;
        if (!td.act[k]) { r = 0; e = 0; }
        td.roff[k] = r * ROW;
        unsigned pk = c_edge[e];
        td.pi[k] = pk & 0xffff;
        td.ci[k] = pk >> 16;
        td.me[k] = e;
    }

    float l1 = 0.f, vel = 0.f;
    float4 p0, p1, p2, t0, t1, t2;

    // prologue: issue chunk-0 loads (plain vector loads -> VGPR)
    p0 = ldg4(gp + l4);       p1 = ldg4(gp + 256 + l4);
    t0 = ldg4(gt + l4);       t1 = ldg4(gt + 256 + l4);
    if (tail) { p2 = ldg4(gp + 512 + l4); t2 = ldg4(gt + 512 + l4); }

#pragma unroll
    for (int c = 0; c < CHUNKS; ++c) {
        // stage chunk c to LDS (compiler inserts the vmcnt for reg arrival)
        st4(B + l4,                 p0);
        st4(B + 256 + l4,           p1);
        st4(B + CHUNK_DW + l4,      t0);
        st4(B + CHUNK_DW + 256 + l4, t1);
        if (tail) {
            st4(B + 512 + l4,            p2);
            st4(B + CHUNK_DW + 512 + l4, t2);
        }

        // l1 term directly from the staging registers (no LDS read)
        acc_l1(p0, t0, l1);
        acc_l1(p1, t1, l1);
        if (tail) acc_l1(p2, t2, l1);

        // issue chunk c+1 loads now; latency hides under the edge gather
        if (c + 1 < CHUNKS) {
            const float* cp = gp + (c + 1) * CHUNK_DW;
            const float* ct = gt + (c + 1) * CHUNK_DW;
            p0 = ldg4(cp + l4);       p1 = ldg4(cp + 256 + l4);
            t0 = ldg4(ct + l4);       t1 = ldg4(ct + 256 + l4);
            if (tail) { p2 = ldg4(cp + 512 + l4); t2 = ldg4(ct + 512 + l4); }
        }

        // edge gather from LDS (compiler inserts lgkmcnt for the ds RAW)
        compute_edges(B, td, vel);
        // next iteration's ds_writes are ordered after this wave's ds_reads
        // by the in-order per-wave DS pipe (single-wave-private buffer).
    }

    // ---- block reduction -> per-block partials ----
#pragma unroll
    for (int off = 32; off > 0; off >>= 1) {
        l1  += __shfl_down(l1, off);
        vel += __shfl_down(vel, off);
    }
    if (lane == 0) { redL[wave] = l1; redV[wave] = vel; }
    __syncthreads();
    if (t == 0) {
        wsL[blockIdx.x] = redL[0] + redL[1] + redL[2] + redL[3];
        wsV[blockIdx.x] = redV[0] + redV[1] + redV[2] + redV[3];
    }
}

__global__ __launch_bounds__(BLOCK) void reg_loss_finalize(
        const float* __restrict__ wsL, const float* __restrict__ wsV,
        float* __restrict__ out) {
    __shared__ double rl[4], rv[4];
    const int t = threadIdx.x;
    const int lane = t & 63;
    const int wave = t >> 6;
    double L = 0.0, V = 0.0;
    for (int k = t; k < GRID; k += BLOCK) { L += wsL[k]; V += wsV[k]; }
#pragma unroll
    for (int off = 32; off > 0; off >>= 1) {
        L += __shfl_down(L, off);
        V += __shfl_down(V, off);
    }
    if (lane == 0) { rl[wave] = L; rv[wave] = V; }
    __syncthreads();
    if (t == 0) {
        double Ls = rl[0] + rl[1] + rl[2] + rl[3];
        double Vs = rv[0] + rv[1] + rv[2] + rv[3];
        out[0] = (float)(Ls / ((double)N_ROWS * 151.0)
                       + 0.1 * (Vs / ((double)N_ROWS * 141.0)));
    }
}

extern "C" void kernel_launch(void* const* d_in, const int* in_sizes, int n_in,
                              void* d_out, int out_size, void* d_ws, size_t ws_size,
                              hipStream_t stream) {
    const float* preds   = (const float*)d_in[0];
    const float* targets = (const float*)d_in[1];
    float* wsL = (float*)d_ws;
    float* wsV = wsL + GRID;
    float* out = (float*)d_out;

    reg_loss_main<<<GRID, BLOCK, 0, stream>>>(preds, targets, wsL, wsV);
    reg_loss_finalize<<<1, BLOCK, 0, stream>>>(wsL, wsV, out);
}

// Round 3
// 178.665 us; speedup vs baseline: 1.0912x; 1.0912x over previous
//
#include <hip/hip_runtime.h>

// RegLoss: l1(masked preds, targets) + 0.1 * mse(masked edge directions)
// preds, targets: [128, 1024, 151] fp32. Output: 1 fp32 scalar.
//
// Identities:
//   targets * (targets != 0) == targets       (masking targets is identity)
//   (m*pd - m*td)^2 == m*(pd - td)^2          (m in {0,1})
//   diff/(len+tiny) == (d2 > 0 ? diff*rsq(d2) : 0)  (~1e-7 rel; thresh 2.4e-2)
//
// R9: R8's plain-load structure with REGISTER HEADROOM. R8 failed because
// __launch_bounds__(256,8) capped VGPR at 64 and the allocator pinned 32 +
// spilled the 24-VGPR staging block to scratch: WRITE_SIZE 130KB -> 43.8MB,
// FETCH +35MB, 63 -> 80us. Yet aggregate traffic (158MB useful + ~79MB
// spill in 80us ~= 3.0 TB/s) EXCEEDED the 2.5 TB/s wall both global_load_lds
// rounds sat on (R6==R7 identical at 2 different occupancies => serving-rate
// cap on the LDS-DMA return path, not latency). So: keep the plain-load
// path, give it registers.
//   - __launch_bounds__(256,4): VGPR cap 128, 4 blocks/CU (16 waves/CU) --
//     R6's exact occupancy shape, proven not the limiter => clean A/B of
//     load path at equal concurrency.
//   - tail (368B) loads made divergence-free: clamped address, uncond load,
//     masked use. Removes undef-phi pressure on the allocator.
// Per chunk: regs arrive -> ds_write x6 -> l1 from regs (no LDS read) ->
// issue chunk c+1 loads -> edge gather from LDS.

#define N_ROWS   (128 * 1024)
#define ROW      151
#define N_EDGES  47
#define GRID     2048
#define BLOCK    256
#define CHUNKS   4                     // 2048 blk * 4 waves * 4 chunks * 4 rows
#define CHUNK_ROWS 4
#define CHUNK_DW (CHUNK_ROWS * ROW)    // 604 dwords per array per chunk
#define CHUNK_TASKS (CHUNK_ROWS * N_EDGES) // 188
#define BUF_DW (2 * CHUNK_DW)          // [preds 604][targets 604] = 4832 B

#if __has_builtin(__builtin_amdgcn_rsqf)
__device__ __forceinline__ float fast_rsq(float x) { return __builtin_amdgcn_rsqf(x); }
#else
__device__ __forceinline__ float fast_rsq(float x) {
    float r; asm volatile("v_rsq_f32 %0, %1" : "=v"(r) : "v"(x)); return r;
}
#endif

__device__ __forceinline__ float4 ldg4(const float* __restrict__ p) {
    return *reinterpret_cast<const float4*>(p);
}
__device__ __forceinline__ void st4(float* __restrict__ p, float4 v) {
    *reinterpret_cast<float4*>(p) = v;
}

// packed: low16 = parent*3 (dword offset in row), high16 = child*3
#define E(p, c) ((unsigned)((p) * 3) | ((unsigned)((c) * 3) << 16))
__constant__ unsigned c_edge[N_EDGES] = {
    E(0,1),  E(1,2),  E(2,3),  E(3,29), E(1,5),  E(5,6),  E(6,8),  E(8,9),
    E(8,13), E(8,17), E(8,21), E(8,25), E(9,10), E(10,11),E(11,12),E(13,14),
    E(14,15),E(15,16),E(17,18),E(18,19),E(19,20),E(21,22),E(22,23),E(23,24),
    E(25,26),E(26,27),E(27,28),E(29,30),E(29,34),E(29,38),E(29,42),E(29,46),
    E(30,31),E(31,32),E(32,33),E(34,35),E(35,36),E(36,37),E(38,39),E(39,40),
    E(40,41),E(42,43),E(43,44),E(44,45),E(46,47),E(47,48),E(48,49)};

struct TaskDesc { int act[3], roff[3], pi[3], ci[3], me[3]; };

__device__ __forceinline__ void acc_l1(float4 pv, float4 tv, float& l1) {
    float a0 = (tv.x != 0.f) ? pv.x : 0.f;
    float a1 = (tv.y != 0.f) ? pv.y : 0.f;
    float a2 = (tv.z != 0.f) ? pv.z : 0.f;
    float a3 = (tv.w != 0.f) ? pv.w : 0.f;
    l1 += fabsf(a0 - tv.x) + fabsf(a1 - tv.y)
        + fabsf(a2 - tv.z) + fabsf(a3 - tv.w);
}

// 188 edge tasks from LDS, mask applied at read time.
__device__ __forceinline__ void compute_edges(
        const float* __restrict__ B, const TaskDesc& td, float& vel) {
    const float* __restrict__ Bp = B;
    const float* __restrict__ Bt = B + CHUNK_DW;
#pragma unroll
    for (int k = 0; k < 3; ++k) {
        if (td.act[k]) {
            const float* __restrict__ Rp = Bp + td.roff[k];
            const float* __restrict__ Rt = Bt + td.roff[k];
            int pi = td.pi[k], ci = td.ci[k], me = td.me[k];
            float tpx = Rt[pi], tpy = Rt[pi + 1], tpz = Rt[pi + 2];
            float tcx = Rt[ci], tcy = Rt[ci + 1], tcz = Rt[ci + 2];
            float ppx = Rp[pi], ppy = Rp[pi + 1], ppz = Rp[pi + 2];
            float pcx = Rp[ci], pcy = Rp[ci + 1], pcz = Rp[ci + 2];
            // masked preds
            float apx = (tpx != 0.f) ? ppx : 0.f;
            float apy = (tpy != 0.f) ? ppy : 0.f;
            float apz = (tpz != 0.f) ? ppz : 0.f;
            float acx = (tcx != 0.f) ? pcx : 0.f;
            float acy = (tcy != 0.f) ? pcy : 0.f;
            float acz = (tcz != 0.f) ? pcz : 0.f;
            float pdx = apx - acx, pdy = apy - acy, pdz = apz - acz;
            float tdx = tpx - tcx, tdy = tpy - tcy, tdz = tpz - tcz;
            float pd2 = pdx * pdx + pdy * pdy + pdz * pdz;
            float td2 = tdx * tdx + tdy * tdy + tdz * tdz;
            float pinv = (pd2 > 0.f) ? fast_rsq(pd2) : 0.f;
            float tinv = (td2 > 0.f) ? fast_rsq(td2) : 0.f;
            float dx = pdx * pinv - tdx * tinv;
            float dy = pdy * pinv - tdy * tinv;
            float dz = pdz * pinv - tdz * tinv;
            float m0 = (Rt[me]      != 0.f) ? 1.f : 0.f;
            float m1 = (Rt[me + 47] != 0.f) ? 1.f : 0.f;
            float m2 = (Rt[me + 94] != 0.f) ? 1.f : 0.f;
            vel += m0 * dx * dx + m1 * dy * dy + m2 * dz * dz;
        }
    }
}

__global__ __launch_bounds__(BLOCK, 4) void reg_loss_main(
        const float* __restrict__ preds, const float* __restrict__ targets,
        float* __restrict__ wsL, float* __restrict__ wsV) {
    __shared__ float S[4][BUF_DW];         // 4 waves x 4832B = 19.3 KB/block
    __shared__ float redL[4], redV[4];

    const int t = threadIdx.x;
    const int lane = t & 63;
    const int wave = t >> 6;
    float* B = &S[wave][0];

    const long long wb =
        (long long)(blockIdx.x * 4 + wave) * (CHUNKS * CHUNK_DW);
    const float* gp = preds + wb;
    const float* gt = targets + wb;

    const int l4 = lane * 4;
    const bool tail = lane < 23;           // 23*16B = 368B tail (604-512 dw)
    const int off2 = tail ? (512 + l4) : l4;   // clamped: lanes >=23 re-read
                                               // lane-local bytes (L1 hit),
                                               // results masked at use.

    // per-lane edge-task descriptors (fixed across chunks)
    TaskDesc td;
#pragma unroll
    for (int k = 0; k < 3; ++k) {
        int task = lane + k * 64;
        td.act[k] = task < CHUNK_TASKS;
        int r = task / N_EDGES;
        int e = task - r * N_EDGES;
        if (!td.act[k]) { r = 0; e = 0; }
        td.roff[k] = r * ROW;
        unsigned pk = c_edge[e];
        td.pi[k] = pk & 0xffff;
        td.ci[k] = pk >> 16;
        td.me[k] = e;
    }

    float l1 = 0.f, vel = 0.f;
    float4 p0, p1, p2, t0, t1, t2;

    // prologue: issue chunk-0 loads (plain vector loads -> VGPR)
    p0 = ldg4(gp + l4);       p1 = ldg4(gp + 256 + l4);
    t0 = ldg4(gt + l4);       t1 = ldg4(gt + 256 + l4);
    p2 = ldg4(gp + off2);     t2 = ldg4(gt + off2);

#pragma unroll
    for (int c = 0; c < CHUNKS; ++c) {
        // stage chunk c to LDS (compiler inserts the vmcnt for reg arrival)
        st4(B + l4,                  p0);
        st4(B + 256 + l4,            p1);
        st4(B + CHUNK_DW + l4,       t0);
        st4(B + CHUNK_DW + 256 + l4, t1);
        if (tail) {
            st4(B + 512 + l4,            p2);
            st4(B + CHUNK_DW + 512 + l4, t2);
        }

        // l1 term directly from the staging registers (no LDS read)
        acc_l1(p0, t0, l1);
        acc_l1(p1, t1, l1);
        if (tail) acc_l1(p2, t2, l1);

        // issue chunk c+1 loads now; latency hides under the edge gather
        if (c + 1 < CHUNKS) {
            const float* cp = gp + (c + 1) * CHUNK_DW;
            const float* ct = gt + (c + 1) * CHUNK_DW;
            p0 = ldg4(cp + l4);       p1 = ldg4(cp + 256 + l4);
            t0 = ldg4(ct + l4);       t1 = ldg4(ct + 256 + l4);
            p2 = ldg4(cp + off2);     t2 = ldg4(ct + off2);
        }

        // edge gather from LDS (compiler inserts lgkmcnt for the ds RAW)
        compute_edges(B, td, vel);
        // next iteration's ds_writes are ordered after this wave's ds_reads
        // by the in-order per-wave DS pipe (single-wave-private buffer).
    }

    // ---- block reduction -> per-block partials ----
#pragma unroll
    for (int off = 32; off > 0; off >>= 1) {
        l1  += __shfl_down(l1, off);
        vel += __shfl_down(vel, off);
    }
    if (lane == 0) { redL[wave] = l1; redV[wave] = vel; }
    __syncthreads();
    if (t == 0) {
        wsL[blockIdx.x] = redL[0] + redL[1] + redL[2] + redL[3];
        wsV[blockIdx.x] = redV[0] + redV[1] + redV[2] + redV[3];
    }
}

__global__ __launch_bounds__(BLOCK) void reg_loss_finalize(
        const float* __restrict__ wsL, const float* __restrict__ wsV,
        float* __restrict__ out) {
    __shared__ double rl[4], rv[4];
    const int t = threadIdx.x;
    const int lane = t & 63;
    const int wave = t >> 6;
    double L = 0.0, V = 0.0;
    for (int k = t; k < GRID; k += BLOCK) { L += wsL[k]; V += wsV[k]; }
#pragma unroll
    for (int off = 32; off > 0; off >>= 1) {
        L += __shfl_down(L, off);
        V += __shfl_down(V, off);
    }
    if (lane == 0) { rl[wave] = L; rv[wave] = V; }
    __syncthreads();
    if (t == 0) {
        double Ls = rl[0] + rl[1] + rl[2] + rl[3];
        double Vs = rv[0] + rv[1] + rv[2] + rv[3];
        out[0] = (float)(Ls / ((double)N_ROWS * 151.0)
                       + 0.1 * (Vs / ((double)N_ROWS * 141.0)));
    }
}

extern "C" void kernel_launch(void* const* d_in, const int* in_sizes, int n_in,
                              void* d_out, int out_size, void* d_ws, size_t ws_size,
                              hipStream_t stream) {
    const float* preds   = (const float*)d_in[0];
    const float* targets = (const float*)d_in[1];
    float* wsL = (float*)d_ws;
    float* wsV = wsL + GRID;
    float* out = (float*)d_out;

    reg_loss_main<<<GRID, BLOCK, 0, stream>>>(preds, targets, wsL, wsV);
    reg_loss_finalize<<<1, BLOCK, 0, stream>>>(wsL, wsV, out);
}

// Round 4
// 178.578 us; speedup vs baseline: 1.0917x; 1.0005x over previous
//
#include <hip/hip_runtime.h>

// RegLoss: l1(masked preds, targets) + 0.1 * mse(masked edge directions)
// preds, targets: [128, 1024, 151] fp32. Output: 1 fp32 scalar.
//
// Identities:
//   targets * (targets != 0) == targets       (masking targets is identity)
//   (m*pd - m*td)^2 == m*(pd - td)^2          (m in {0,1})
//   diff/(len+tiny) == (d2 > 0 ? diff*rsq(d2) : 0)  (~1e-7 rel; thresh 2.4e-2)
//
// R10: pin the prefetch with sched_barrier(0). Evidence so far:
//   R6 DMA depth-2 16w/CU  = 63.5us   R7 DMA depth-1 32w/CU = 63.5us
//   R9 reg-path 16w/CU     = 63.5us   (VGPR_Count=40 => compiler SANK the
//   prefetch loads to right before their ds_write use; the "overlap" never
//   existed in the emitted code -- same burst-load/stall/compute shape as
//   the DMA rounds). R8 (spilling) pushed 2.96 TB/s through the CU port,
//   so 2.49 TB/s is NOT a hard memory wall; the invariant across clean
//   rounds is per-wave shape: 4.8KB burst -> full-latency stall -> ~700cy
//   compute with nothing in flight. Queueing math: waves wait ~90% of
//   their lifetime. Fix = real issue-early overlap.
//
// Mechanism: __builtin_amdgcn_sched_barrier(0) after the next-chunk load
// issue and before the edge gather. Nothing crosses a sched_barrier(0),
// so the 6 global_load_dwordx4 are issued before the ~600cy LDS edge
// phase, and their latency hides under it. __launch_bounds__(256,4)
// (VGPR cap 128) gives the allocator room for the 24 live staging regs +
// edge temps (~70 peak) without spilling; 16 waves/CU, proven not the
// limiter (R6 vs R7). Descriptor slimmed 15 -> 9 regs (pre-summed LDS
// addresses; lane-activity recomputed from lane, free).
//
// Checkable signature: VGPR_Count must rise to ~64-84 (pin worked) and
// WRITE_SIZE stay ~130KB (no spills). If both hold and duration is still
// ~63.5us, the full {path x depth x waves} matrix saturates at 2.49 TB/s
// => serving-rate roofline for this pattern.

#define N_ROWS   (128 * 1024)
#define ROW      151
#define N_EDGES  47
#define GRID     2048
#define BLOCK    256
#define CHUNKS   4                     // 2048 blk * 4 waves * 4 chunks * 4 rows
#define CHUNK_ROWS 4
#define CHUNK_DW (CHUNK_ROWS * ROW)    // 604 dwords per array per chunk
#define CHUNK_TASKS (CHUNK_ROWS * N_EDGES) // 188
#define BUF_DW (2 * CHUNK_DW)          // [preds 604][targets 604] = 4832 B

#if __has_builtin(__builtin_amdgcn_rsqf)
__device__ __forceinline__ float fast_rsq(float x) { return __builtin_amdgcn_rsqf(x); }
#else
__device__ __forceinline__ float fast_rsq(float x) {
    float r; asm volatile("v_rsq_f32 %0, %1" : "=v"(r) : "v"(x)); return r;
}
#endif

__device__ __forceinline__ float4 ldg4(const float* __restrict__ p) {
    return *reinterpret_cast<const float4*>(p);
}
__device__ __forceinline__ void st4(float* __restrict__ p, float4 v) {
    *reinterpret_cast<float4*>(p) = v;
}

// packed: low16 = parent*3 (dword offset in row), high16 = child*3
#define E(p, c) ((unsigned)((p) * 3) | ((unsigned)((c) * 3) << 16))
__constant__ unsigned c_edge[N_EDGES] = {
    E(0,1),  E(1,2),  E(2,3),  E(3,29), E(1,5),  E(5,6),  E(6,8),  E(8,9),
    E(8,13), E(8,17), E(8,21), E(8,25), E(9,10), E(10,11),E(11,12),E(13,14),
    E(14,15),E(15,16),E(17,18),E(18,19),E(19,20),E(21,22),E(22,23),E(23,24),
    E(25,26),E(26,27),E(27,28),E(29,30),E(29,34),E(29,38),E(29,42),E(29,46),
    E(30,31),E(31,32),E(32,33),E(34,35),E(35,36),E(36,37),E(38,39),E(39,40),
    E(40,41),E(42,43),E(43,44),E(44,45),E(46,47),E(47,48),E(48,49)};

// pre-summed LDS dword addresses: aP/aC = row_off + joint*3, aM = row_off + e
struct EdgeAddr { int aP[3], aC[3], aM[3]; };

__device__ __forceinline__ void acc_l1(float4 pv, float4 tv, float& l1) {
    float a0 = (tv.x != 0.f) ? pv.x : 0.f;
    float a1 = (tv.y != 0.f) ? pv.y : 0.f;
    float a2 = (tv.z != 0.f) ? pv.z : 0.f;
    float a3 = (tv.w != 0.f) ? pv.w : 0.f;
    l1 += fabsf(a0 - tv.x) + fabsf(a1 - tv.y)
        + fabsf(a2 - tv.z) + fabsf(a3 - tv.w);
}

// 188 edge tasks from LDS, mask applied at read time.
// k=0,1 fully active (tasks 0..127); k=2 active for lane<60 (tasks 128..187).
__device__ __forceinline__ void compute_edges(
        const float* __restrict__ B, const EdgeAddr& ea, int lane, float& vel) {
    const float* __restrict__ Bp = B;
    const float* __restrict__ Bt = B + CHUNK_DW;
#pragma unroll
    for (int k = 0; k < 3; ++k) {
        if (k < 2 || lane < (CHUNK_TASKS - 128)) {
            int aP = ea.aP[k], aC = ea.aC[k], aM = ea.aM[k];
            float tpx = Bt[aP], tpy = Bt[aP + 1], tpz = Bt[aP + 2];
            float tcx = Bt[aC], tcy = Bt[aC + 1], tcz = Bt[aC + 2];
            float ppx = Bp[aP], ppy = Bp[aP + 1], ppz = Bp[aP + 2];
            float pcx = Bp[aC], pcy = Bp[aC + 1], pcz = Bp[aC + 2];
            // masked preds
            float apx = (tpx != 0.f) ? ppx : 0.f;
            float apy = (tpy != 0.f) ? ppy : 0.f;
            float apz = (tpz != 0.f) ? ppz : 0.f;
            float acx = (tcx != 0.f) ? pcx : 0.f;
            float acy = (tcy != 0.f) ? pcy : 0.f;
            float acz = (tcz != 0.f) ? pcz : 0.f;
            float pdx = apx - acx, pdy = apy - acy, pdz = apz - acz;
            float tdx = tpx - tcx, tdy = tpy - tcy, tdz = tpz - tcz;
            float pd2 = pdx * pdx + pdy * pdy + pdz * pdz;
            float td2 = tdx * tdx + tdy * tdy + tdz * tdz;
            float pinv = (pd2 > 0.f) ? fast_rsq(pd2) : 0.f;
            float tinv = (td2 > 0.f) ? fast_rsq(td2) : 0.f;
            float dx = pdx * pinv - tdx * tinv;
            float dy = pdy * pinv - tdy * tinv;
            float dz = pdz * pinv - tdz * tinv;
            float m0 = (Bt[aM]      != 0.f) ? 1.f : 0.f;
            float m1 = (Bt[aM + 47] != 0.f) ? 1.f : 0.f;
            float m2 = (Bt[aM + 94] != 0.f) ? 1.f : 0.f;
            vel += m0 * dx * dx + m1 * dy * dy + m2 * dz * dz;
        }
    }
}

__global__ __launch_bounds__(BLOCK, 4) void reg_loss_main(
        const float* __restrict__ preds, const float* __restrict__ targets,
        float* __restrict__ wsL, float* __restrict__ wsV) {
    __shared__ float S[4][BUF_DW];         // 4 waves x 4832B = 19.3 KB/block
    __shared__ float redL[4], redV[4];

    const int t = threadIdx.x;
    const int lane = t & 63;
    const int wave = t >> 6;
    float* B = &S[wave][0];

    const long long wb =
        (long long)(blockIdx.x * 4 + wave) * (CHUNKS * CHUNK_DW);
    const float* gp = preds + wb;
    const float* gt = targets + wb;

    const int l4 = lane * 4;
    const bool tail = lane < 23;           // 23*16B = 368B tail (604-512 dw)
    const int off2 = tail ? (512 + l4) : l4;   // clamped: lanes >=23 re-read
                                               // lane-local bytes (L1 hit),
                                               // results masked at use.

    // per-lane edge-task addresses (fixed across chunks): 9 VGPRs
    EdgeAddr ea;
#pragma unroll
    for (int k = 0; k < 3; ++k) {
        int task = lane + k * 64;
        bool a = task < CHUNK_TASKS;
        int r = a ? task / N_EDGES : 0;
        int e = a ? task - r * N_EDGES : 0;
        int roff = r * ROW;
        unsigned pk = c_edge[e];
        ea.aP[k] = roff + (int)(pk & 0xffff);
        ea.aC[k] = roff + (int)(pk >> 16);
        ea.aM[k] = roff + e;
    }

    float l1 = 0.f, vel = 0.f;
    float4 p0, p1, p2, t0, t1, t2;

    // prologue: issue chunk-0 loads (plain vector loads -> VGPR)
    p0 = ldg4(gp + l4);       p1 = ldg4(gp + 256 + l4);
    t0 = ldg4(gt + l4);       t1 = ldg4(gt + 256 + l4);
    p2 = ldg4(gp + off2);     t2 = ldg4(gt + off2);

#pragma unroll
    for (int c = 0; c < CHUNKS; ++c) {
        // stage chunk c to LDS (compiler inserts the vmcnt for reg arrival)
        st4(B + l4,                  p0);
        st4(B + 256 + l4,            p1);
        st4(B + CHUNK_DW + l4,       t0);
        st4(B + CHUNK_DW + 256 + l4, t1);
        if (tail) {
            st4(B + 512 + l4,            p2);
            st4(B + CHUNK_DW + 512 + l4, t2);
        }

        // l1 term directly from the staging registers (no LDS read)
        acc_l1(p0, t0, l1);
        acc_l1(p1, t1, l1);
        if (tail) acc_l1(p2, t2, l1);

        // issue chunk c+1 loads NOW; the sched_barrier below forbids the
        // scheduler from sinking them past the edge phase, so their latency
        // hides under ~600cy of LDS gather + VALU.
        if (c + 1 < CHUNKS) {
            const float* cp = gp + (c + 1) * CHUNK_DW;
            const float* ct = gt + (c + 1) * CHUNK_DW;
            p0 = ldg4(cp + l4);       p1 = ldg4(cp + 256 + l4);
            t0 = ldg4(ct + l4);       t1 = ldg4(ct + 256 + l4);
            p2 = ldg4(cp + off2);     t2 = ldg4(ct + off2);
        }
        __builtin_amdgcn_sched_barrier(0);   // pin: loads issued before edges

        // edge gather from LDS (same-wave DS ordering vs the st4s above)
        compute_edges(B, ea, lane, vel);
    }

    // ---- block reduction -> per-block partials ----
#pragma unroll
    for (int off = 32; off > 0; off >>= 1) {
        l1  += __shfl_down(l1, off);
        vel += __shfl_down(vel, off);
    }
    if (lane == 0) { redL[wave] = l1; redV[wave] = vel; }
    __syncthreads();
    if (t == 0) {
        wsL[blockIdx.x] = redL[0] + redL[1] + redL[2] + redL[3];
        wsV[blockIdx.x] = redV[0] + redV[1] + redV[2] + redV[3];
    }
}

__global__ __launch_bounds__(BLOCK) void reg_loss_finalize(
        const float* __restrict__ wsL, const float* __restrict__ wsV,
        float* __restrict__ out) {
    __shared__ double rl[4], rv[4];
    const int t = threadIdx.x;
    const int lane = t & 63;
    const int wave = t >> 6;
    double L = 0.0, V = 0.0;
    for (int k = t; k < GRID; k += BLOCK) { L += wsL[k]; V += wsV[k]; }
#pragma unroll
    for (int off = 32; off > 0; off >>= 1) {
        L += __shfl_down(L, off);
        V += __shfl_down(V, off);
    }
    if (lane == 0) { rl[wave] = L; rv[wave] = V; }
    __syncthreads();
    if (t == 0) {
        double Ls = rl[0] + rl[1] + rl[2] + rl[3];
        double Vs = rv[0] + rv[1] + rv[2] + rv[3];
        out[0] = (float)(Ls / ((double)N_ROWS * 151.0)
                       + 0.1 * (Vs / ((double)N_ROWS * 141.0)));
    }
}

extern "C" void kernel_launch(void* const* d_in, const int* in_sizes, int n_in,
                              void* d_out, int out_size, void* d_ws, size_t ws_size,
                              hipStream_t stream) {
    const float* preds   = (const float*)d_in[0];
    const float* targets = (const float*)d_in[1];
    float* wsL = (float*)d_ws;
    float* wsV = wsL + GRID;
    float* out = (float*)d_out;

    reg_loss_main<<<GRID, BLOCK, 0, stream>>>(preds, targets, wsL, wsV);
    reg_loss_finalize<<<1, BLOCK, 0, stream>>>(wsL, wsV, out);
}